// Round 2
// baseline (255.866 us; speedup 1.0000x reference)
//
#include <hip/hip_runtime.h>

// x [B=8, C=2, D=16, T=128000] fp32, x_wave [B=8, D=16, T=128000] fp32,
// pad_left = pad_right = 8, WINDOW=8, L=16, k=2.
//
// Identity: output p = seg*8 + dd gets
//   x[b,c,dd,seg]*w[b,dd,seg] + x[b,c,dd+8,seg-1]*w[b,dd+8,seg-1],
// valid segs 1..T-1.
//
// Round-2 theory: both prior kernels (scalar/67% occ and float4/LDS/35% occ)
// saturate at 1.94 TB/s HBM -> not MLP, not occupancy, not traffic. Common
// factor: every block reads 1KB chunks of 48 rows strided 512KB apart ->
// ~50k concurrent fine-grained streams, DRAM row-buffer thrash. This version
// quadruples per-stream run length (SEGS=1024 -> 4KB/row/block) and quarters
// stream count. Two c-passes through one 66KB LDS product buffer; w held in
// registers across passes (fetched once); c=1 x rows prefetched into regs
// before the first barrier so gather(c=0) overlaps the c=1 read.
// LDS 65,792 B -> 2 blocks/CU (8 waves/CU); BW shown occupancy-insensitive.

constexpr int B = 8;
constexpr int C = 2;
constexpr int D = 16;
constexpr int T = 128000;

constexpr int SEGS  = 1024;          // segs per block; 4KB run per row
constexpr int PITCH = 1028;          // floats; 4112 B, 16B-aligned rows
constexpr int NBLK  = T / SEGS;      // 125

__global__ __launch_bounds__(256, 2) void oaa_longrun_kernel(
    const float* __restrict__ x,
    const float* __restrict__ xw,
    float* __restrict__ out,
    int S)
{
    __shared__ float P[D][PITCH];    // products for ONE c; tloc = t-(s0-4); 65,792 B

    const int j    = threadIdx.x;
    const int lane = j & 63;
    const int wv   = j >> 6;         // wave 0..3 owns rows 4*wv..4*wv+3
    const int b    = blockIdx.y;
    const int s0   = blockIdx.x * SEGS;

    const float* __restrict__ xwb = xw + (size_t)b * D * T;
    const float* __restrict__ xb0 = x  + (size_t)b * C * D * T;  // c=0
    const float* __restrict__ xb1 = xb0 + (size_t)D * T;         // c=1

    float4 W[4][4];                  // w rows, reused for both c
    float4 X1[4][4];                 // c=1 prefetch
    float  wh = 0.f, xh1 = 0.f;      // halo (threads j<8, rows 8..15, t=s0-1)

    // ---- pass A: load w + x(c=0) as 4KB-per-row runs, products -> LDS ----
#pragma unroll
    for (int r = 0; r < 4; ++r) {
        const int d = 4 * wv + r;
        const float* wp = xwb + (size_t)d * T + s0 + 4 * lane;
        const float* xp = xb0 + (size_t)d * T + s0 + 4 * lane;
        float4 X0[4];
#pragma unroll
        for (int q = 0; q < 4; ++q) W[r][q] = *(const float4*)(wp + 256 * q);
#pragma unroll
        for (int q = 0; q < 4; ++q) X0[q]   = *(const float4*)(xp + 256 * q);
#pragma unroll
        for (int q = 0; q < 4; ++q) {
            float4 pr;
            pr.x = W[r][q].x * X0[q].x;
            pr.y = W[r][q].y * X0[q].y;
            pr.z = W[r][q].z * X0[q].z;
            pr.w = W[r][q].w * X0[q].w;
            *(float4*)&P[d][4 + 256 * q + 4 * lane] = pr;   // ds_write_b128, contiguous
        }
    }
    // halo t = s0-1 for rows 8..15 lands at tloc=3 (= sloc 0's term-1 slot).
    // Block 0 clamps to t=0: garbage, but only seg 0 reads it and seg 0 is masked.
    if (j < 8) {
        const int dh = 8 + j;
        const size_t th = (s0 > 0) ? (size_t)(s0 - 1) : 0;
        wh  = xwb[(size_t)dh * T + th];
        const float xh0 = xb0[(size_t)dh * T + th];
        xh1 = xb1[(size_t)dh * T + th];
        P[dh][3] = wh * xh0;
    }
    // ---- prefetch x(c=1): in flight across the c=0 gather ----
#pragma unroll
    for (int r = 0; r < 4; ++r) {
        const int d = 4 * wv + r;
        const float* xp = xb1 + (size_t)d * T + s0 + 4 * lane;
#pragma unroll
        for (int q = 0; q < 4; ++q) X1[r][q] = *(const float4*)(xp + 256 * q);
    }
    __syncthreads();

    // ---- gather + store c=0 (contiguous 1KB/wave stores) ----
    const size_t ob = (size_t)b * C * S;
#pragma unroll
    for (int i = 0; i < 8; ++i) {
        const int sig  = j + 256 * i;          // 0..2047
        const int half = sig & 1;
        const int sloc = sig >> 1;             // 0..1023
        const int seg  = s0 + sloc;
        if (seg != 0) {
            const int dbase = 4 * half;
            const int ta = sloc + 4;           // t = seg
            const int tb = sloc + 3;           // t = seg-1 (sloc=0 -> halo slot)
            float4 o;
            o.x = P[dbase + 0][ta] + P[dbase +  8][tb];
            o.y = P[dbase + 1][ta] + P[dbase +  9][tb];
            o.z = P[dbase + 2][ta] + P[dbase + 10][tb];
            o.w = P[dbase + 3][ta] + P[dbase + 11][tb];
            *(float4*)(out + ob + (size_t)seg * 8 - 8 + dbase) = o;
        }
    }
    __syncthreads();

    // ---- pass B: products for c=1 from prefetched regs (w from regs) ----
#pragma unroll
    for (int r = 0; r < 4; ++r) {
        const int d = 4 * wv + r;
#pragma unroll
        for (int q = 0; q < 4; ++q) {
            float4 pr;
            pr.x = W[r][q].x * X1[r][q].x;
            pr.y = W[r][q].y * X1[r][q].y;
            pr.z = W[r][q].z * X1[r][q].z;
            pr.w = W[r][q].w * X1[r][q].w;
            *(float4*)&P[d][4 + 256 * q + 4 * lane] = pr;
        }
    }
    if (j < 8) P[8 + j][3] = wh * xh1;
    __syncthreads();

    // ---- gather + store c=1 ----
#pragma unroll
    for (int i = 0; i < 8; ++i) {
        const int sig  = j + 256 * i;
        const int half = sig & 1;
        const int sloc = sig >> 1;
        const int seg  = s0 + sloc;
        if (seg != 0) {
            const int dbase = 4 * half;
            const int ta = sloc + 4;
            const int tb = sloc + 3;
            float4 o;
            o.x = P[dbase + 0][ta] + P[dbase +  8][tb];
            o.y = P[dbase + 1][ta] + P[dbase +  9][tb];
            o.z = P[dbase + 2][ta] + P[dbase + 10][tb];
            o.w = P[dbase + 3][ta] + P[dbase + 11][tb];
            *(float4*)(out + ob + (size_t)S + (size_t)seg * 8 - 8 + dbase) = o;
        }
    }
}

extern "C" void kernel_launch(void* const* d_in, const int* in_sizes, int n_in,
                              void* d_out, int out_size, void* d_ws, size_t ws_size,
                              hipStream_t stream) {
    const float* x  = (const float*)d_in[0];
    const float* xw = (const float*)d_in[1];
    float* out = (float*)d_out;

    const int S = out_size / (B * C);          // 1023992 floats per (b,c)
    dim3 grid(NBLK, B);                        // 125 x 8 = 1000 blocks
    oaa_longrun_kernel<<<grid, dim3(256), 0, stream>>>(x, xw, out, S);
}